// Round 8
// baseline (55.203 us; speedup 1.0000x reference)
//
#include <hip/hip_runtime.h>
#include <hip/hip_fp16.h>

// Output = abs(column 63 after both transforms). Only W1 row 63 and
// P = W2r+W2i, Q = W2r-W2i are needed. Memory-bound: streams x (256 MiB) once.
//
// Structure = round 6 (4 waves cooperate per batch, per-batch lockstep
// barriers keeping each block's reads one tight 32-KiB burst) with ONE
// change: PQt staging moved AFTER phase A. Grid == full residency, so all
// blocks start together; staging-first made the whole chip spend ~2 us on
// L2/W2 reads before the x stream began. Staging now lands in the
// staggered-finish tail where it overlaps other blocks' streaming.
//
// Per-lane math: 8 lanes/row, 8 complexes (64 B)/lane, 3-step butterfly;
// row 0 passthrough of x[b,0,63].
// Phase B: out[b,m] = | sum_n Yr[n]*P[m,n] + Yi[n]*Q[m,n] |, P/Q packed
// half2 in LDS (18.3 KiB/block -> 8 blocks/CU, 32 waves/CU).

typedef float vf4 __attribute__((ext_vector_type(4)));

__global__ __launch_bounds__(256, 8)
void cnet_kernel(const float* __restrict__ x,
                 const float* __restrict__ W1r,
                 const float* __restrict__ W1i,
                 const float* __restrict__ W2r,
                 const float* __restrict__ W2i,
                 float* __restrict__ out) {
    __shared__ __half2 PQt[64 * 65];   // [n][m] = (P[m,n], Q[m,n]); stride 65 dwords
    __shared__ float2  YW[4][64];      // [batch-in-block][n]

    const int tid  = threadIdx.x;
    const int w    = tid >> 6;    // wave id 0..3
    const int lane = tid & 63;
    const int lg   = lane >> 3;   // row within octet (0..7)
    const int li   = lane & 7;    // position within row: complexes 8li..8li+7

    // W1 row 63 coefficients for this lane's 8 columns (8li..8li+7).
    const float4 Aa = ((const float4*)(W1r + 63 * 64))[2 * li];
    const float4 Ab = ((const float4*)(W1r + 63 * 64))[2 * li + 1];
    const float4 Ba = ((const float4*)(W1i + 63 * 64))[2 * li];
    const float4 Bb = ((const float4*)(W1i + 63 * 64))[2 * li + 1];

    // ---- Phase A: block-cooperative, one batch at a time, lockstep ----
    for (int k = 0; k < 4; ++k) {
        const float* xp = x + (size_t)(blockIdx.x * 4 + k) * 8192;
        #pragma unroll
        for (int p = 0; p < 2; ++p) {
            const int n = p * 32 + w * 8 + lg;             // this lane's row
            const float* base = xp + n * 128 + li * 16;
            const vf4 u0 = *(const vf4*)(base);
            const vf4 u1 = *(const vf4*)(base + 4);
            const vf4 u2 = *(const vf4*)(base + 8);
            const vf4 u3 = *(const vf4*)(base + 12);

            float pr = u0.x*Aa.x - u0.y*Ba.x + u0.z*Aa.y - u0.w*Ba.y
                     + u1.x*Aa.z - u1.y*Ba.z + u1.z*Aa.w - u1.w*Ba.w
                     + u2.x*Ab.x - u2.y*Bb.x + u2.z*Ab.y - u2.w*Bb.y
                     + u3.x*Ab.z - u3.y*Bb.z + u3.z*Ab.w - u3.w*Bb.w;
            float pi = u0.y*Aa.x + u0.x*Ba.x + u0.w*Aa.y + u0.z*Ba.y
                     + u1.y*Aa.z + u1.x*Ba.z + u1.w*Aa.w + u1.z*Ba.w
                     + u2.y*Ab.x + u2.x*Bb.x + u2.w*Ab.y + u2.z*Bb.y
                     + u3.y*Ab.z + u3.x*Bb.z + u3.w*Ab.w + u3.z*Bb.w;

            #pragma unroll
            for (int msk = 1; msk < 8; msk <<= 1) {        // reduce within 8-lane groups
                pr += __shfl_xor(pr, msk);
                pi += __shfl_xor(pi, msk);
            }

            if (p == 0 && w == 0) {
                // Row 0 (n==0) is passthrough x[b,0,63,:]: lane 7 holds
                // complexes 56..63 -> complex 63 = u3.z/.w.
                if (lane == 7) YW[k][0] = make_float2(u3.z, u3.w);
                if (li == 0 && lg != 0) YW[k][lg] = make_float2(pr, pi);
            } else if (li == 0) {
                YW[k][n] = make_float2(pr, pi);
            }
        }
        __syncthreads();   // lockstep: keep the block's 4 waves in one burst
    }

    // ---- Stage P/Q packed fp16, transposed (moved post-stream: overlaps
    // other blocks' x traffic in the staggered tail). W2 is L2-resident.
    // Writes at dword stride 65 -> bank = idx%32, conflict-free.
    for (int idx = tid; idx < 4096; idx += 256) {
        const int m = idx >> 6;
        const int n = idx & 63;
        const float wr = W2r[idx];
        const float wi = W2i[idx];
        PQt[n * 65 + m] = __halves2half2(__float2half_rn(wr + wi),
                                         __float2half_rn(wr - wi));
    }

    __syncthreads();   // PQt (and all YW) visible to all waves

    // ---- Phase B: wave w handles batch blockIdx*4+w; lane = output m ----
    float acc = 0.f;
    #pragma unroll 8
    for (int n = 0; n < 64; ++n) {
        const float2  y  = YW[w][n];            // broadcast read
        const __half2 pq = PQt[n * 65 + lane];  // conflict-free b32 read
        acc += y.x * __low2float(pq) + y.y * __high2float(pq);
    }
    out[(size_t)(blockIdx.x * 4 + w) * 64 + lane] = fabsf(acc);
}

extern "C" void kernel_launch(void* const* d_in, const int* in_sizes, int n_in,
                              void* d_out, int out_size, void* d_ws, size_t ws_size,
                              hipStream_t stream) {
    const float* x   = (const float*)d_in[0];
    const float* W1r = (const float*)d_in[1];
    const float* W1i = (const float*)d_in[2];
    const float* W2r = (const float*)d_in[3];
    const float* W2i = (const float*)d_in[4];
    float* o = (float*)d_out;

    const int B = in_sizes[0] / (64 * 64 * 2);   // 8192 batches
    const int nblocks = B / 4;                   // 4 batches per block
    hipLaunchKernelGGL(cnet_kernel, dim3(nblocks), dim3(256), 0, stream,
                       x, W1r, W1i, W2r, W2i, o);
}

// Round 9
// 50.090 us; speedup vs baseline: 1.1021x; 1.1021x over previous
//
#include <hip/hip_runtime.h>
#include <hip/hip_fp16.h>

// Output = abs(column 63 after both transforms). Only W1 row 63 and
// P = W2r+W2i, Q = W2r-W2i are needed. Memory-bound: streams x (256 MiB) once.
//
// Structure = round 6 (4 waves cooperate per batch, per-batch lockstep
// barriers keep each block's reads one tight 32-KiB sequential burst;
// PQt staged in the prologue where it overlaps the stream ramp) with ONE
// change: 8 batches per block (1024 blocks, 4 blocks/CU). Halves the
// chip-wide staging work and the concurrent-stream count; 16 waves/CU
// still gives 64 KiB/CU of loads in flight (~7x the latency-BW product).
//
// Per-lane math: 8 lanes/row, 8 complexes (64 B)/lane, 3-step butterfly;
// row 0 passthrough of x[b,0,63].
// Phase B: out[b,m] = | sum_n Yr[n]*P[m,n] + Yi[n]*Q[m,n] |, P/Q packed
// half2 in LDS (20.6 KiB/block).

typedef float vf4 __attribute__((ext_vector_type(4)));

__global__ __launch_bounds__(256, 4)
void cnet_kernel(const float* __restrict__ x,
                 const float* __restrict__ W1r,
                 const float* __restrict__ W1i,
                 const float* __restrict__ W2r,
                 const float* __restrict__ W2i,
                 float* __restrict__ out) {
    __shared__ __half2 PQt[64 * 65];   // [n][m] = (P[m,n], Q[m,n]); stride 65 dwords
    __shared__ float2  YW[8][64];      // [batch-in-block][n]

    const int tid  = threadIdx.x;
    const int w    = tid >> 6;    // wave id 0..3
    const int lane = tid & 63;
    const int lg   = lane >> 3;   // row within octet (0..7)
    const int li   = lane & 7;    // position within row: complexes 8li..8li+7

    // Stage P/Q packed fp16, transposed (prologue: overlaps stream ramp).
    // Coalesced W2 reads; writes at dword stride 65 -> bank = idx%32,
    // conflict-free.
    for (int idx = tid; idx < 4096; idx += 256) {
        const int m = idx >> 6;
        const int n = idx & 63;
        const float wr = W2r[idx];
        const float wi = W2i[idx];
        PQt[n * 65 + m] = __halves2half2(__float2half_rn(wr + wi),
                                         __float2half_rn(wr - wi));
    }

    // W1 row 63 coefficients for this lane's 8 columns (8li..8li+7).
    const float4 Aa = ((const float4*)(W1r + 63 * 64))[2 * li];
    const float4 Ab = ((const float4*)(W1r + 63 * 64))[2 * li + 1];
    const float4 Ba = ((const float4*)(W1i + 63 * 64))[2 * li];
    const float4 Bb = ((const float4*)(W1i + 63 * 64))[2 * li + 1];

    __syncthreads();

    // ---- Phase A: block-cooperative, one batch at a time, lockstep ----
    for (int k = 0; k < 8; ++k) {
        const float* xp = x + (size_t)(blockIdx.x * 8 + k) * 8192;
        #pragma unroll
        for (int p = 0; p < 2; ++p) {
            const int n = p * 32 + w * 8 + lg;             // this lane's row
            const float* base = xp + n * 128 + li * 16;
            const vf4 u0 = *(const vf4*)(base);
            const vf4 u1 = *(const vf4*)(base + 4);
            const vf4 u2 = *(const vf4*)(base + 8);
            const vf4 u3 = *(const vf4*)(base + 12);

            float pr = u0.x*Aa.x - u0.y*Ba.x + u0.z*Aa.y - u0.w*Ba.y
                     + u1.x*Aa.z - u1.y*Ba.z + u1.z*Aa.w - u1.w*Ba.w
                     + u2.x*Ab.x - u2.y*Bb.x + u2.z*Ab.y - u2.w*Bb.y
                     + u3.x*Ab.z - u3.y*Bb.z + u3.z*Ab.w - u3.w*Bb.w;
            float pi = u0.y*Aa.x + u0.x*Ba.x + u0.w*Aa.y + u0.z*Ba.y
                     + u1.y*Aa.z + u1.x*Ba.z + u1.w*Aa.w + u1.z*Ba.w
                     + u2.y*Ab.x + u2.x*Bb.x + u2.w*Ab.y + u2.z*Bb.y
                     + u3.y*Ab.z + u3.x*Bb.z + u3.w*Ab.w + u3.z*Bb.w;

            #pragma unroll
            for (int msk = 1; msk < 8; msk <<= 1) {        // reduce within 8-lane groups
                pr += __shfl_xor(pr, msk);
                pi += __shfl_xor(pi, msk);
            }

            if (p == 0 && w == 0) {
                // Row 0 (n==0) is passthrough x[b,0,63,:]: lane 7 holds
                // complexes 56..63 -> complex 63 = u3.z/.w.
                if (lane == 7) YW[k][0] = make_float2(u3.z, u3.w);
                if (li == 0 && lg != 0) YW[k][lg] = make_float2(pr, pi);
            } else if (li == 0) {
                YW[k][n] = make_float2(pr, pi);
            }
        }
        __syncthreads();   // lockstep: keep the block's 4 waves in one burst
    }

    // ---- Phase B: wave w handles batches k = w and k = w+4 ----
    #pragma unroll
    for (int j = 0; j < 2; ++j) {
        const int k = w + j * 4;
        float acc = 0.f;
        #pragma unroll 8
        for (int n = 0; n < 64; ++n) {
            const float2  y  = YW[k][n];            // broadcast read
            const __half2 pq = PQt[n * 65 + lane];  // conflict-free b32 read
            acc += y.x * __low2float(pq) + y.y * __high2float(pq);
        }
        out[(size_t)(blockIdx.x * 8 + k) * 64 + lane] = fabsf(acc);
    }
}

extern "C" void kernel_launch(void* const* d_in, const int* in_sizes, int n_in,
                              void* d_out, int out_size, void* d_ws, size_t ws_size,
                              hipStream_t stream) {
    const float* x   = (const float*)d_in[0];
    const float* W1r = (const float*)d_in[1];
    const float* W1i = (const float*)d_in[2];
    const float* W2r = (const float*)d_in[3];
    const float* W2i = (const float*)d_in[4];
    float* o = (float*)d_out;

    const int B = in_sizes[0] / (64 * 64 * 2);   // 8192 batches
    const int nblocks = B / 8;                   // 8 batches per block
    hipLaunchKernelGGL(cnet_kernel, dim3(nblocks), dim3(256), 0, stream,
                       x, W1r, W1i, W2r, W2i, o);
}

// Round 10
// 46.260 us; speedup vs baseline: 1.1933x; 1.0828x over previous
//
#include <hip/hip_runtime.h>
#include <hip/hip_fp16.h>

// Output = abs(column 63 after both transforms). Only W1 row 63 and
// P = W2r+W2i, Q = W2r-W2i are needed. Memory-bound: streams x (256 MiB) once.
//
// BEST VARIANT (round 6, reverted after r7/r8/r9 regressions):
//  - 4 waves cooperate on one batch at a time; per-batch lockstep
//    __syncthreads keeps each block's reads one tight 32-KiB sequential
//    burst (8 streams/CU). Removing the barriers (r7), moving staging to
//    the epilogue (r8), or halving occupancy (r9) all regressed.
//  - PQt staged in the prologue (overlaps the stream ramp); half2-packed,
//    transposed, stride-65 -> 18.3 KiB/block, 8 blocks/CU, 32 waves/CU,
//    zero bank conflicts.
//  - Per-lane math: 8 lanes/row, 8 complexes (64 B)/lane, 3-step butterfly;
//    row 0 passthrough of x[b,0,63].
//  - Phase B: out[b,m] = | sum_n Yr[n]*P[m,n] + Yi[n]*Q[m,n] |.
// 46.2 us = 5.86 TB/s effective = 93% of measured copy ceiling. Roofline.

typedef float vf4 __attribute__((ext_vector_type(4)));

__global__ __launch_bounds__(256, 8)
void cnet_kernel(const float* __restrict__ x,
                 const float* __restrict__ W1r,
                 const float* __restrict__ W1i,
                 const float* __restrict__ W2r,
                 const float* __restrict__ W2i,
                 float* __restrict__ out) {
    __shared__ __half2 PQt[64 * 65];   // [n][m] = (P[m,n], Q[m,n]); stride 65 dwords
    __shared__ float2  YW[4][64];      // [batch-in-block][n]

    const int tid  = threadIdx.x;
    const int w    = tid >> 6;    // wave id 0..3
    const int lane = tid & 63;
    const int lg   = lane >> 3;   // row within octet (0..7)
    const int li   = lane & 7;    // position within row: complexes 8li..8li+7

    // Stage P/Q packed fp16, transposed. Coalesced W2 reads; writes at
    // dword stride 65 -> bank = idx%32, conflict-free.
    for (int idx = tid; idx < 4096; idx += 256) {
        const int m = idx >> 6;
        const int n = idx & 63;
        const float wr = W2r[idx];
        const float wi = W2i[idx];
        PQt[n * 65 + m] = __halves2half2(__float2half_rn(wr + wi),
                                         __float2half_rn(wr - wi));
    }

    // W1 row 63 coefficients for this lane's 8 columns (8li..8li+7).
    const float4 Aa = ((const float4*)(W1r + 63 * 64))[2 * li];
    const float4 Ab = ((const float4*)(W1r + 63 * 64))[2 * li + 1];
    const float4 Ba = ((const float4*)(W1i + 63 * 64))[2 * li];
    const float4 Bb = ((const float4*)(W1i + 63 * 64))[2 * li + 1];

    __syncthreads();

    // ---- Phase A: block-cooperative, one batch at a time, lockstep ----
    for (int k = 0; k < 4; ++k) {
        const float* xp = x + (size_t)(blockIdx.x * 4 + k) * 8192;
        #pragma unroll
        for (int p = 0; p < 2; ++p) {
            const int n = p * 32 + w * 8 + lg;             // this lane's row
            const float* base = xp + n * 128 + li * 16;
            const vf4 u0 = *(const vf4*)(base);
            const vf4 u1 = *(const vf4*)(base + 4);
            const vf4 u2 = *(const vf4*)(base + 8);
            const vf4 u3 = *(const vf4*)(base + 12);

            float pr = u0.x*Aa.x - u0.y*Ba.x + u0.z*Aa.y - u0.w*Ba.y
                     + u1.x*Aa.z - u1.y*Ba.z + u1.z*Aa.w - u1.w*Ba.w
                     + u2.x*Ab.x - u2.y*Bb.x + u2.z*Ab.y - u2.w*Bb.y
                     + u3.x*Ab.z - u3.y*Bb.z + u3.z*Ab.w - u3.w*Bb.w;
            float pi = u0.y*Aa.x + u0.x*Ba.x + u0.w*Aa.y + u0.z*Ba.y
                     + u1.y*Aa.z + u1.x*Ba.z + u1.w*Aa.w + u1.z*Ba.w
                     + u2.y*Ab.x + u2.x*Bb.x + u2.w*Ab.y + u2.z*Bb.y
                     + u3.y*Ab.z + u3.x*Bb.z + u3.w*Ab.w + u3.z*Bb.w;

            #pragma unroll
            for (int msk = 1; msk < 8; msk <<= 1) {        // reduce within 8-lane groups
                pr += __shfl_xor(pr, msk);
                pi += __shfl_xor(pi, msk);
            }

            if (p == 0 && w == 0) {
                // Row 0 (n==0) is passthrough x[b,0,63,:]: lane 7 holds
                // complexes 56..63 -> complex 63 = u3.z/.w.
                if (lane == 7) YW[k][0] = make_float2(u3.z, u3.w);
                if (li == 0 && lg != 0) YW[k][lg] = make_float2(pr, pi);
            } else if (li == 0) {
                YW[k][n] = make_float2(pr, pi);
            }
        }
        __syncthreads();   // lockstep: keep the block's 4 waves in one burst
    }

    // ---- Phase B: wave w handles batch blockIdx*4+w; lane = output m ----
    float acc = 0.f;
    #pragma unroll 8
    for (int n = 0; n < 64; ++n) {
        const float2  y  = YW[w][n];            // broadcast read
        const __half2 pq = PQt[n * 65 + lane];  // conflict-free b32 read
        acc += y.x * __low2float(pq) + y.y * __high2float(pq);
    }
    out[(size_t)(blockIdx.x * 4 + w) * 64 + lane] = fabsf(acc);
}

extern "C" void kernel_launch(void* const* d_in, const int* in_sizes, int n_in,
                              void* d_out, int out_size, void* d_ws, size_t ws_size,
                              hipStream_t stream) {
    const float* x   = (const float*)d_in[0];
    const float* W1r = (const float*)d_in[1];
    const float* W1i = (const float*)d_in[2];
    const float* W2r = (const float*)d_in[3];
    const float* W2i = (const float*)d_in[4];
    float* o = (float*)d_out;

    const int B = in_sizes[0] / (64 * 64 * 2);   // 8192 batches
    const int nblocks = B / 4;                   // 4 batches per block
    hipLaunchKernelGGL(cnet_kernel, dim3(nblocks), dim3(256), 0, stream,
                       x, W1r, W1i, W2r, W2i, o);
}